// Round 2
// baseline (231.178 us; speedup 1.0000x reference)
//
#include <hip/hip_runtime.h>

// SymmetricChannel: out[b,l,:] = one_hot(shifted replacement) if
// (rand_u[b,l] < P && argmax(message[b,l,:]) != 0) else message[b,l,:].
// V=128 floats per row; 32 lanes per row, float4 per lane.
//
// Launch shape per G11 (memory-bound): fixed 2048-block grid-stride loop
// (was 32768 tiny one-shot blocks -> CP dispatch serialization), 2-way
// unroll so two NT loads are in flight before either store (ILP on top of
// TLP). Half-wave uniformity invariants:
//   - stride = gridDim*blockDim is a multiple of 64, so slot&31 == lane
//     and each half-wave's 32 slots cover exactly one row.
//   - total = n_rows*32, so the loop guard never splits a half-wave.
// Therefore the ru<P branch and the shfl_xor(width=32) butterfly always
// execute with the full half-wave active.

constexpr int V = 128;
constexpr float P = 0.1f;

typedef float f4 __attribute__((ext_vector_type(4)));

__global__ __launch_bounds__(256) void SymmetricChannel_kernel(
    const float* __restrict__ msg,
    const float* __restrict__ rand_u,
    const int*   __restrict__ rep_idx,
    float*       __restrict__ out,
    long long total)            // n_rows * 32 slots
{
    const long long stride = (long long)gridDim.x * blockDim.x;
    const long long tid    = (long long)blockIdx.x * blockDim.x + threadIdx.x;
    const int lane32 = threadIdx.x & 31;   // == slot & 31 for every slot below
    const int base   = lane32 * 4;

    // Per-slot compute: copy, or one-hot replacement on the corrupt path.
    auto compute = [&](f4 v, float ru, long long row) -> f4 {
        f4 o = v;
        if (ru < P) {
            float best = v.x; int bidx = 0;
            if (v.y > best) { best = v.y; bidx = 1; }
            if (v.z > best) { best = v.z; bidx = 2; }
            if (v.w > best) { best = v.w; bidx = 3; }
            int gidx = base + bidx;
            #pragma unroll
            for (int m = 16; m > 0; m >>= 1) {
                float ov = __shfl_xor(best, m, 32);
                int   oi = __shfl_xor(gidx, m, 32);
                if (ov > best || (ov == best && oi < gidx)) { best = ov; gidx = oi; }
            }
            int am = gidx;                  // argmax(message[row])
            if (am != 0) {
                int r1  = rep_idx[row] + 1;
                int sym = r1 + (r1 >= am ? 1 : 0);
                o.x = (base + 0 == sym) ? 1.0f : 0.0f;
                o.y = (base + 1 == sym) ? 1.0f : 0.0f;
                o.z = (base + 2 == sym) ? 1.0f : 0.0f;
                o.w = (base + 3 == sym) ? 1.0f : 0.0f;
            }
        }
        return o;
    };

    for (long long s = tid; s < total; s += 2 * stride) {
        long long sB   = s + stride;
        bool hasB      = sB < total;        // half-wave uniform (see header)
        long long rowA = s >> 5;
        long long rowB = hasB ? (sB >> 5) : rowA;   // safe fallback addr

        // Issue both loads before any store (32 B in flight / thread).
        f4 vA = __builtin_nontemporal_load((const f4*)(msg + rowA * V) + lane32);
        f4 vB = __builtin_nontemporal_load((const f4*)(msg + rowB * V) + lane32);
        float ruA = rand_u[rowA];
        float ruB = rand_u[rowB];

        f4 oA = compute(vA, ruA, rowA);
        __builtin_nontemporal_store(oA, (f4*)(out + rowA * V) + lane32);
        if (hasB) {
            f4 oB = compute(vB, ruB, rowB);
            __builtin_nontemporal_store(oB, (f4*)(out + rowB * V) + lane32);
        }
    }
}

extern "C" void kernel_launch(void* const* d_in, const int* in_sizes, int n_in,
                              void* d_out, int out_size, void* d_ws, size_t ws_size,
                              hipStream_t stream) {
    const float* msg = (const float*)d_in[0];   // [B, L, V] f32
    const float* ru  = (const float*)d_in[1];   // [B, L]    f32
    const int*   ri  = (const int*)d_in[2];     // [B, L]    i32
    float* out = (float*)d_out;                 // [B, L, V] f32

    long long n_rows = in_sizes[1];             // B*L
    long long total  = n_rows * 32;             // 32 lanes per row
    int threads = 256;
    long long want = (total + threads - 1) / threads;
    int blocks = (int)(want < 2048 ? want : 2048);   // 256 CU x 8 blocks
    SymmetricChannel_kernel<<<blocks, threads, 0, stream>>>(msg, ru, ri, out, total);
}

// Round 3
// 224.357 us; speedup vs baseline: 1.0304x; 1.0304x over previous
//
#include <hip/hip_runtime.h>

// SymmetricChannel: out[b,l,:] = one_hot(shifted replacement) if
// (rand_u[b,l] < P && argmax(message[b,l,:]) != 0) else message[b,l,:].
// V=128 floats per row.
//
// Shape: 8 lanes per row, 4x float4 per lane (64 B in flight per thread,
// 4 independent loads issued before any store -> ILP on top of TLP), one-shot
// blocks (Round 2 showed grid-stride loop overhead costs more than it saves).
// Block count 8192 (4x fewer than 32-lane/row variant).
//
// ru < P is uniform per 8-lane row-group, so the shfl_xor(width=8) butterfly
// only ever runs with its whole group active. Local 16-elem argmax scans in
// ascending global-index order with strict '>' => first-occurrence tie-break;
// cross-lane combine prefers smaller index on ties (jnp.argmax semantics).

constexpr int V = 128;
constexpr float P = 0.1f;

typedef float f4 __attribute__((ext_vector_type(4)));

__global__ __launch_bounds__(256) void SymmetricChannel_kernel(
    const float* __restrict__ msg,
    const float* __restrict__ rand_u,
    const int*   __restrict__ rep_idx,
    float*       __restrict__ out,
    int n_rows)
{
    int tid   = blockIdx.x * blockDim.x + threadIdx.x;
    int row   = tid >> 3;          // 8 lanes per row
    int lane8 = tid & 7;
    if (row >= n_rows) return;

    const f4* mrow = (const f4*)(msg + (size_t)row * V);
    // f4 indices handled by this lane: lane8, lane8+8, lane8+16, lane8+24.
    f4 v0 = __builtin_nontemporal_load(mrow + lane8);
    f4 v1 = __builtin_nontemporal_load(mrow + lane8 + 8);
    f4 v2 = __builtin_nontemporal_load(mrow + lane8 + 16);
    f4 v3 = __builtin_nontemporal_load(mrow + lane8 + 24);
    float ru = rand_u[row];        // uniform across the 8-lane group

    f4 o0 = v0, o1 = v1, o2 = v2, o3 = v3;

    if (ru < P) {
        // Local argmax over 16 elems. Global element index of f4 #k elem e:
        // (lane8 + 8k)*4 + e — strictly increasing in scan order below.
        const int b0 = (lane8     ) * 4;
        const int b1 = (lane8 +  8) * 4;
        const int b2 = (lane8 + 16) * 4;
        const int b3 = (lane8 + 24) * 4;
        float best = v0.x; int gidx = b0;
        auto upd = [&](float val, int gi) {
            if (val > best) { best = val; gidx = gi; }
        };
        upd(v0.y, b0 + 1); upd(v0.z, b0 + 2); upd(v0.w, b0 + 3);
        upd(v1.x, b1    ); upd(v1.y, b1 + 1); upd(v1.z, b1 + 2); upd(v1.w, b1 + 3);
        upd(v2.x, b2    ); upd(v2.y, b2 + 1); upd(v2.z, b2 + 2); upd(v2.w, b2 + 3);
        upd(v3.x, b3    ); upd(v3.y, b3 + 1); upd(v3.z, b3 + 2); upd(v3.w, b3 + 3);

        // Butterfly over the 8-lane group; smaller index wins ties.
        #pragma unroll
        for (int m = 4; m > 0; m >>= 1) {
            float ov = __shfl_xor(best, m, 8);
            int   oi = __shfl_xor(gidx, m, 8);
            if (ov > best || (ov == best && oi < gidx)) { best = ov; gidx = oi; }
        }

        int am = gidx;             // argmax(message[row])
        if (am != 0) {
            int r1  = rep_idx[row] + 1;
            int sym = r1 + (r1 >= am ? 1 : 0);
            auto onehot = [&](int base) -> f4 {
                f4 r;
                r.x = (base + 0 == sym) ? 1.0f : 0.0f;
                r.y = (base + 1 == sym) ? 1.0f : 0.0f;
                r.z = (base + 2 == sym) ? 1.0f : 0.0f;
                r.w = (base + 3 == sym) ? 1.0f : 0.0f;
                return r;
            };
            o0 = onehot(b0); o1 = onehot(b1); o2 = onehot(b2); o3 = onehot(b3);
        }
    }

    f4* orow = (f4*)(out + (size_t)row * V);
    __builtin_nontemporal_store(o0, orow + lane8);
    __builtin_nontemporal_store(o1, orow + lane8 + 8);
    __builtin_nontemporal_store(o2, orow + lane8 + 16);
    __builtin_nontemporal_store(o3, orow + lane8 + 24);
}

extern "C" void kernel_launch(void* const* d_in, const int* in_sizes, int n_in,
                              void* d_out, int out_size, void* d_ws, size_t ws_size,
                              hipStream_t stream) {
    const float* msg = (const float*)d_in[0];   // [B, L, V] f32
    const float* ru  = (const float*)d_in[1];   // [B, L]    f32
    const int*   ri  = (const int*)d_in[2];     // [B, L]    i32
    float* out = (float*)d_out;                 // [B, L, V] f32

    int n_rows = in_sizes[1];                   // B*L
    int threads = 256;
    long long total = (long long)n_rows * 8;    // 8 lanes per row
    int blocks = (int)((total + threads - 1) / threads);
    SymmetricChannel_kernel<<<blocks, threads, 0, stream>>>(msg, ru, ri, out, n_rows);
}